// Round 17
// baseline (214.664 us; speedup 1.0000x reference)
//
#include <hip/hip_runtime.h>
#include <stdint.h>

#define NH 8
#define HD 64
#define BATCH 8
#define SEQ 2048
#define DM 512
#define TOK (BATCH * SEQ)

// softmax scale folded into Q at QKV-GEMM epilogue: 1/sqrt(64) * log2(e)
#define QSCALE 0.18033688011112042f

typedef __attribute__((ext_vector_type(8))) __bf16 bf16x8;
typedef __attribute__((ext_vector_type(4))) float f32x4;
typedef __attribute__((ext_vector_type(16))) float f32x16;
typedef __attribute__((ext_vector_type(8))) uint16_t u16x8;

__device__ __forceinline__ uint16_t f2bf(float f) {
  union { __bf16 h; uint16_t u; } c;
  c.h = (__bf16)f;  // RNE via v_cvt
  return c.u;
}

__device__ __forceinline__ void load_lds16(const void* g, void* l) {
  __builtin_amdgcn_global_load_lds(
      (const __attribute__((address_space(1))) void*)g,
      (__attribute__((address_space(3))) void*)l, 16, 0, 0);
}

// force-drain all outstanding global/buffer loads (incl. global_load_lds DMA)
#define VM_DRAIN() asm volatile("s_waitcnt vmcnt(0)" ::: "memory")

// XOR swizzle for tiles with 128B row stride: byte = (row*128+kbyte) ^ ((row&7)<<4)
__device__ __forceinline__ int swz128(int row, int kbyte) {
  return (row * 128 + kbyte) ^ ((row & 7) << 4);
}

#define MFMA16(a, b, c) __builtin_amdgcn_mfma_f32_16x16x32_bf16(a, b, c, 0, 0, 0)
#define MFMA32(a, b, c) __builtin_amdgcn_mfma_f32_32x32x16_bf16(a, b, c, 0, 0, 0)

// ---------------- LayerNorm + cast to bf16 (1 wave / row) ----------------
__global__ __launch_bounds__(256) void ln_kernel(
    const float* __restrict__ x, const float* __restrict__ gam,
    const float* __restrict__ bet, uint16_t* __restrict__ xn) {
  const int row = blockIdx.x * 4 + (threadIdx.x >> 6);
  const int lane = threadIdx.x & 63;
  const float4* xr = (const float4*)(x + (size_t)row * DM);
  float4 a0 = xr[lane * 2 + 0];
  float4 a1 = xr[lane * 2 + 1];
  float s = a0.x + a0.y + a0.z + a0.w + a1.x + a1.y + a1.z + a1.w;
  float q = a0.x * a0.x + a0.y * a0.y + a0.z * a0.z + a0.w * a0.w +
            a1.x * a1.x + a1.y * a1.y + a1.z * a1.z + a1.w * a1.w;
#pragma unroll
  for (int m = 1; m < 64; m <<= 1) {
    s += __shfl_xor(s, m);
    q += __shfl_xor(q, m);
  }
  const float mean = s * (1.0f / DM);
  const float var = q * (1.0f / DM) - mean * mean;
  const float rstd = rsqrtf(var + 1e-5f);
  const float4* gv = (const float4*)gam;
  const float4* bv = (const float4*)bet;
  float4 g0 = gv[lane * 2], g1 = gv[lane * 2 + 1];
  float4 b0 = bv[lane * 2], b1 = bv[lane * 2 + 1];
  u16x8 r;
  r[0] = f2bf((a0.x - mean) * rstd * g0.x + b0.x);
  r[1] = f2bf((a0.y - mean) * rstd * g0.y + b0.y);
  r[2] = f2bf((a0.z - mean) * rstd * g0.z + b0.z);
  r[3] = f2bf((a0.w - mean) * rstd * g0.w + b0.w);
  r[4] = f2bf((a1.x - mean) * rstd * g1.x + b1.x);
  r[5] = f2bf((a1.y - mean) * rstd * g1.y + b1.y);
  r[6] = f2bf((a1.z - mean) * rstd * g1.z + b1.z);
  r[7] = f2bf((a1.w - mean) * rstd * g1.w + b1.w);
  *(u16x8*)(xn + (size_t)row * DM + lane * 8) = r;
}

// ---------------- weight fp32 -> bf16 cast ----------------
__global__ __launch_bounds__(256) void cast_w(const float* __restrict__ w,
                                              uint16_t* __restrict__ o, int n8) {
  int i = blockIdx.x * 256 + threadIdx.x;
  if (i >= n8) return;
  const float4* p = (const float4*)w + (size_t)i * 2;
  float4 a0 = p[0], a1 = p[1];
  u16x8 r;
  r[0] = f2bf(a0.x); r[1] = f2bf(a0.y); r[2] = f2bf(a0.z); r[3] = f2bf(a0.w);
  r[4] = f2bf(a1.x); r[5] = f2bf(a1.y); r[6] = f2bf(a1.z); r[7] = f2bf(a1.w);
  *(u16x8*)(o + (size_t)i * 8) = r;
}

// ---------------- bf16 NT GEMM: C[M,N] = A[M,512] * Bw[N,512]^T + bias ----------------
// 128x128 tile, BK=64, 4 waves (2x2 of 64x64), global_load_lds w/ pre-swizzled src.
// EPI==0: scatter to Q[BH][S][64] (pre-scaled by QSCALE), K[BH][S][64], V^T[BH][64][S]
// EPI==1: C fp32 row-major [M][512]
template <int EPI>
__global__ __launch_bounds__(256) void gemm_nt(
    const uint16_t* __restrict__ A, const uint16_t* __restrict__ Bw,
    const float* __restrict__ bias, uint16_t* __restrict__ oq,
    uint16_t* __restrict__ okk, uint16_t* __restrict__ ov,
    float* __restrict__ oc) {
  __shared__ __align__(16) char As[128 * 64 * 2];
  __shared__ __align__(16) char Bs[128 * 64 * 2];
  const int tid = threadIdx.x;
  const int lane = tid & 63;
  const int w = tid >> 6;
  const int wr = (w >> 1) * 64;
  const int wc = (w & 1) * 64;
  const int l15 = lane & 15;
  const int l4 = lane >> 4;
  const size_t tileM = (size_t)blockIdx.y * 128;
  const int tileN = blockIdx.x * 128;
  const int trow = tid >> 3;
  const int tcol = tid & 7;
  const f32x4 vzero = {0.f, 0.f, 0.f, 0.f};

  f32x4 acc[4][4];
#pragma unroll
  for (int m = 0; m < 4; ++m)
#pragma unroll
    for (int n = 0; n < 4; ++n) acc[m][n] = vzero;

  for (int kt = 0; kt < 8; ++kt) {
    if (kt) __syncthreads();
#pragma unroll
    for (int i = 0; i < 4; ++i) {
      const int row = i * 32 + trow;
      const int c0 = 8 * (tcol ^ (row & 7));  // pre-swizzled source column
      load_lds16(A + (tileM + row) * DM + kt * 64 + c0, As + i * 4096 + w * 1024);
      load_lds16(Bw + (size_t)(tileN + row) * DM + kt * 64 + c0, Bs + i * 4096 + w * 1024);
    }
    VM_DRAIN();
    __syncthreads();
#pragma unroll
    for (int ks = 0; ks < 2; ++ks) {
      const int kb = ks * 64 + l4 * 16;
      bf16x8 af[4], bfr[4];
#pragma unroll
      for (int m = 0; m < 4; ++m) {
        const int r = wr + m * 16 + l15;
        af[m] = *(const bf16x8*)(As + swz128(r, kb));
      }
#pragma unroll
      for (int n = 0; n < 4; ++n) {
        const int r = wc + n * 16 + l15;
        bfr[n] = *(const bf16x8*)(Bs + swz128(r, kb));
      }
#pragma unroll
      for (int m = 0; m < 4; ++m)
#pragma unroll
        for (int n = 0; n < 4; ++n)
          acc[m][n] = MFMA16(af[m], bfr[n], acc[m][n]);
    }
  }

#pragma unroll
  for (int m = 0; m < 4; ++m) {
    const size_t row0 = tileM + wr + m * 16 + l4 * 4;
#pragma unroll
    for (int n = 0; n < 4; ++n) {
      const int col = tileN + wc + n * 16 + l15;
      const float bb = bias[col];
#pragma unroll
      for (int jj = 0; jj < 4; ++jj) {
        const float val = acc[m][n][jj] + bb;
        const size_t r = row0 + jj;
        if (EPI == 0) {
          const int wh = col >> 9;
          const int rem = col & 511;
          const int h = rem >> 6;
          const int dd = rem & 63;
          const int bi = (int)(r >> 11);
          const int si = (int)(r & 2047);
          const size_t bh = (size_t)bi * NH + h;
          if (wh == 0)
            oq[(bh * SEQ + si) * HD + dd] = f2bf(val * QSCALE);  // exp2-domain Q
          else if (wh == 1)
            okk[(bh * SEQ + si) * HD + dd] = f2bf(val);
          else
            ov[(bh * HD + dd) * SEQ + si] = f2bf(val);  // V stored transposed
        } else {
          oc[r * DM + col] = val;
        }
      }
    }
  }
}

// ---------------- flash attention: 1 block = 128 Q rows of one (b,h) ----------------
// Round-17: EXACT round-16 kernel (best: attn 141us, VALUBusy 72% = VALU-saturated)
// with ONE change: exact skip-rescale. When no lane's row-max grew, corr==1.0 bitwise
// and the rescale pass (exp2 + corrbuf LDS transpose + 32 muls) is a no-op -> skip.
// ~87% of tiles skip (running max grows ~H_32~4 times). r11 tested this in a
// latency-bound regime (null mechanism); r16 is VALU-bound, where VALU-op removal
// is the mechanism that pays (catalog rule #23). lsum keeps the fma form with
// corr=1.0 on the skip path (exact add) -> math bitwise-equivalent.
__global__ __launch_bounds__(256, 4) void attn_kernel(
    const uint16_t* __restrict__ qb, const uint16_t* __restrict__ kb,
    const uint16_t* __restrict__ vb, uint16_t* __restrict__ ab) {
  __shared__ __align__(16) char Ks[2 * 64 * 128];  // [buf][k 64][d 64] bf16, swizzled
  __shared__ __align__(16) char Vs[2 * 64 * 128];  // [buf][d 64][k 64] bf16 (V^T), swizzled
  __shared__ float corrbuf[4 * 32];                // per-wave transpose slot
  const int tid = threadIdx.x;
  const int lane = tid & 63;
  const int wq = tid >> 6;       // wave 0..3 owns q rows wq*32..wq*32+31
  const int l31 = lane & 31;
  const int h = lane >> 5;       // half-wave
  const int bh = blockIdx.x >> 4;
  const int qt = blockIdx.x & 15;
  const uint16_t* qp = qb + (size_t)bh * SEQ * HD;
  const uint16_t* kp = kb + (size_t)bh * SEQ * HD;
  const uint16_t* vp = vb + (size_t)bh * HD * SEQ;
  const int trow = tid >> 3;
  const int tcol = tid & 7;

  auto stageK = [&](int tt, char* dst) {
    const int kv0 = tt * 64;
#pragma unroll
    for (int i = 0; i < 2; ++i) {
      const int row = i * 32 + trow;
      const int c0 = 8 * (tcol ^ (row & 7));
      load_lds16(kp + (size_t)(kv0 + row) * HD + c0, dst + i * 4096 + wq * 1024);
    }
  };
  auto stageV = [&](int tt, char* dst) {
    const int kv0 = tt * 64;
#pragma unroll
    for (int i = 0; i < 2; ++i) {
      const int row = i * 32 + trow;
      const int c0 = 8 * (tcol ^ (row & 7));
      load_lds16(vp + (size_t)row * SEQ + kv0 + c0, dst + i * 4096 + wq * 1024);
    }
  };

  // Q fragments (B-operand: B[col=q=lane&31][k=(lane>>5)*8+j]), whole kernel in regs
  bf16x8 qf[4];
  const int q0 = qt * 128 + wq * 32;
#pragma unroll
  for (int c = 0; c < 4; ++c)
    qf[c] = *(const bf16x8*)(qp + (size_t)(q0 + l31) * HD + c * 16 + h * 8);

  f32x16 oacc0, oacc1;
#pragma unroll
  for (int r = 0; r < 16; ++r) { oacc0[r] = 0.f; oacc1[r] = 0.f; }
  float mrow = -1e30f;  // running max for q = q0 + l31 (dup across halves)
  float lsum = 0.f;     // running denominator for q = q0 + l31 (dup across halves)

  // pack 16 P-values into two PV A-fragments; accumulate their fp32 sum into rs
  auto build2 = [&](const f32x16& s, float m, bf16x8* fa, bf16x8* fb, float& rs) {
    uint32_t u[8];
#pragma unroll
    for (int i2 = 0; i2 < 8; ++i2) {
      float plo = exp2f(s[2 * i2] - m);
      float phi = exp2f(s[2 * i2 + 1] - m);
      rs += plo + phi;
      asm("v_cvt_pk_bf16_f32 %0, %1, %2" : "=v"(u[i2]) : "v"(plo), "v"(phi));
    }
    // swap vdst.hi(lanes32-63) <-> vsrc.lo(lanes0-31): builds contiguous-k frag words
    asm("v_permlane32_swap_b32 %0, %1" : "+v"(u[0]), "+v"(u[2]));
    asm("v_permlane32_swap_b32 %0, %1" : "+v"(u[1]), "+v"(u[3]));
    asm("v_permlane32_swap_b32 %0, %1" : "+v"(u[4]), "+v"(u[6]));
    asm("v_permlane32_swap_b32 %0, %1" : "+v"(u[5]), "+v"(u[7]));
    union { uint32_t w[4]; bf16x8 v; } A, B;
    A.w[0] = u[0]; A.w[1] = u[1]; A.w[2] = u[2]; A.w[3] = u[3];
    B.w[0] = u[4]; B.w[1] = u[5]; B.w[2] = u[6]; B.w[3] = u[7];
    *fa = A.v; *fb = B.v;
  };

  // one KV tile: QK^T -> softmax -> PV, reading Kc/Vc
  auto tile = [&](const char* Kc, const char* Vc) {
    f32x16 s0, s1;
#pragma unroll
    for (int r = 0; r < 16; ++r) { s0[r] = 0.f; s1[r] = 0.f; }
#pragma unroll
    for (int c = 0; c < 4; ++c) {
      const int kbyte = c * 32 + h * 16;
      bf16x8 kf0 = *(const bf16x8*)(Kc + swz128(l31, kbyte));
      bf16x8 kf1 = *(const bf16x8*)(Kc + swz128(32 + l31, kbyte));
      s0 = MFMA32(kf0, qf[c], s0);
      s1 = MFMA32(kf1, qf[c], s1);
    }

    float r8[8];
#pragma unroll
    for (int i = 0; i < 8; ++i)
      r8[i] = fmaxf(fmaxf(s0[2 * i], s0[2 * i + 1]), fmaxf(s1[2 * i], s1[2 * i + 1]));
    float mx = fmaxf(fmaxf(fmaxf(r8[0], r8[1]), fmaxf(r8[2], r8[3])),
                     fmaxf(fmaxf(r8[4], r8[5]), fmaxf(r8[6], r8[7])));
    mx = fmaxf(mx, __shfl_xor(mx, 32));

    // exact skip-rescale: if no lane's max grew, corr==1.0 bitwise -> rescale pass
    // (exp2 + corrbuf transpose + 32 muls) is a no-op; skip it. Wave-uniform branch.
    float corr = 1.0f;
    if (__any(mx > mrow)) {
      const float mold = mrow;
      const float mnew = fmaxf(mold, mx);
      corr = exp2f(mold - mnew);
      mrow = mnew;

      // transpose corr (lane-indexed by q) into D-layout via per-wave LDS slot
      corrbuf[wq * 32 + l31] = corr;  // both halves write identical values
      float4 cg[4];
#pragma unroll
      for (int g = 0; g < 4; ++g)
        cg[g] = *(const float4*)(corrbuf + wq * 32 + 8 * g + 4 * h);
#pragma unroll
      for (int rg = 0; rg < 4; ++rg)
#pragma unroll
        for (int rj = 0; rj < 4; ++rj) {
          const float cc = cg[rg][rj];
          const int r = rg * 4 + rj;
          oacc0[r] *= cc; oacc1[r] *= cc;
        }
    }

    // P = exp2(S - m) packed to bf16 PV A-fragments; fp32 row-sum on the side
    float rs = 0.f;
    bf16x8 pa[4];
    build2(s0, mrow, &pa[0], &pa[1], rs);
    build2(s1, mrow, &pa[2], &pa[3], rs);
    rs += __shfl_xor(rs, 32);   // combine k-halves (identical across h after this)
    lsum = lsum * corr + rs;    // corr==1.0 on the skip path -> exact add

#pragma unroll
    for (int i = 0; i < 4; ++i) {
      const int kbyte = i * 32 + h * 16;
      bf16x8 v0 = *(const bf16x8*)(Vc + swz128(l31, kbyte));
      bf16x8 v1 = *(const bf16x8*)(Vc + swz128(32 + l31, kbyte));
      oacc0 = MFMA32(pa[i], v0, oacc0);
      oacc1 = MFMA32(pa[i], v1, oacc1);
    }
  };

  char* K0 = Ks;        char* V0 = Vs;
  char* K1 = Ks + 8192; char* V1 = Vs + 8192;

  stageK(0, K0);
  stageV(0, V0);
  VM_DRAIN();
  __syncthreads();

  for (int t = 0; t < SEQ / 64; t += 2) {
    // body A: compute tile t from buf0; prefetch t+1 into buf1 (full tile in flight)
    stageK(t + 1, K1);
    stageV(t + 1, V1);
    tile(K0, V0);
    VM_DRAIN();       // t+1 landed; all waves done reading buf0
    __syncthreads();

    // body B: compute tile t+1 from buf1; prefetch t+2 into buf0
    if (t + 2 < SEQ / 64) {
      stageK(t + 2, K0);
      stageV(t + 2, V0);
    }
    tile(K1, V1);
    VM_DRAIN();
    __syncthreads();
  }

  // transpose lsum (lane-indexed by q) into D-layout via per-wave LDS slot
  corrbuf[wq * 32 + l31] = lsum;  // both halves write identical values
  __builtin_amdgcn_s_waitcnt(0);  // lgkmcnt(0): wave-local write->read ordering

  // epilogue: normalize and write attn output as [T][512] bf16 (col = head*64+d)
  const int bi = bh >> 3;
  const int head = bh & 7;
#pragma unroll
  for (int r = 0; r < 16; ++r) {
    const int q = (r & 3) + 8 * (r >> 2) + 4 * h;
    const float inv = 1.0f / corrbuf[wq * 32 + q];
    const size_t tok = (size_t)bi * SEQ + qt * 128 + wq * 32 + q;
    ab[tok * DM + head * HD + l31] = f2bf(oacc0[r] * inv);
    ab[tok * DM + head * HD + 32 + l31] = f2bf(oacc1[r] * inv);
  }
}

extern "C" void kernel_launch(void* const* d_in, const int* in_sizes, int n_in,
                              void* d_out, int out_size, void* d_ws, size_t ws_size,
                              hipStream_t stream) {
  const float* x = (const float*)d_in[0];
  const float* gam = (const float*)d_in[1];
  const float* bet = (const float*)d_in[2];
  const float* wqkv = (const float*)d_in[3];
  const float* bqkv = (const float*)d_in[4];
  const float* wout = (const float*)d_in[5];
  const float* bout = (const float*)d_in[6];

  const size_t SZ_XN = (size_t)TOK * DM * 2;               // 16 MiB
  const size_t SZ_WQ = (size_t)3 * DM * DM * 2;            // 1.5 MiB
  const size_t SZ_WO = (size_t)DM * DM * 2;                // 0.5 MiB
  const size_t SZ_HDBUF = (size_t)BATCH * NH * SEQ * HD * 2;  // 16 MiB each

  char* p = (char*)d_ws;
  uint16_t* xn = (uint16_t*)p;      p += SZ_XN;
  uint16_t* wq = (uint16_t*)p;      p += SZ_WQ;
  uint16_t* wo = (uint16_t*)p;      p += SZ_WO;
  uint16_t* qbuf = (uint16_t*)p;    p += SZ_HDBUF;
  uint16_t* kbuf = (uint16_t*)p;    p += SZ_HDBUF;
  uint16_t* vbuf = (uint16_t*)p;    p += SZ_HDBUF;
  uint16_t* abuf = xn;  // xn dead after QKV GEMM; reuse for attention output

  ln_kernel<<<dim3(TOK / 4), dim3(256), 0, stream>>>(x, gam, bet, xn);
  cast_w<<<dim3((3 * DM * DM / 8) / 256), dim3(256), 0, stream>>>(wqkv, wq, 3 * DM * DM / 8);
  cast_w<<<dim3((DM * DM / 8) / 256), dim3(256), 0, stream>>>(wout, wo, DM * DM / 8);
  gemm_nt<0><<<dim3(12, 128), dim3(256), 0, stream>>>(xn, wq, bqkv, qbuf, kbuf, vbuf, nullptr);
  attn_kernel<<<dim3(BATCH * NH * (SEQ / 128)), dim3(256), 0, stream>>>(qbuf, kbuf, vbuf, abuf);
  gemm_nt<1><<<dim3(4, 128), dim3(256), 0, stream>>>(abuf, wo, bout, nullptr, nullptr, nullptr,
                                                     (float*)d_out);
}

// Round 20
// 211.278 us; speedup vs baseline: 1.0160x; 1.0160x over previous
//
#include <hip/hip_runtime.h>
#include <stdint.h>

#define NH 8
#define HD 64
#define BATCH 8
#define SEQ 2048
#define DM 512
#define TOK (BATCH * SEQ)

// softmax scale folded into Q at QKV-GEMM epilogue: 1/sqrt(64) * log2(e)
#define QSCALE 0.18033688011112042f

typedef __attribute__((ext_vector_type(8))) __bf16 bf16x8;
typedef __attribute__((ext_vector_type(4))) float f32x4;
typedef __attribute__((ext_vector_type(16))) float f32x16;
typedef __attribute__((ext_vector_type(8))) uint16_t u16x8;

__device__ __forceinline__ uint16_t f2bf(float f) {
  union { __bf16 h; uint16_t u; } c;
  c.h = (__bf16)f;  // RNE via v_cvt
  return c.u;
}

__device__ __forceinline__ void load_lds16(const void* g, void* l) {
  __builtin_amdgcn_global_load_lds(
      (const __attribute__((address_space(1))) void*)g,
      (__attribute__((address_space(3))) void*)l, 16, 0, 0);
}

// force-drain all outstanding global/buffer loads (incl. global_load_lds DMA)
#define VM_DRAIN() asm volatile("s_waitcnt vmcnt(0)" ::: "memory")

// XOR swizzle for tiles with 128B row stride: byte = (row*128+kbyte) ^ ((row&7)<<4)
__device__ __forceinline__ int swz128(int row, int kbyte) {
  return (row * 128 + kbyte) ^ ((row & 7) << 4);
}

#define MFMA16(a, b, c) __builtin_amdgcn_mfma_f32_16x16x32_bf16(a, b, c, 0, 0, 0)
#define MFMA32(a, b, c) __builtin_amdgcn_mfma_f32_32x32x16_bf16(a, b, c, 0, 0, 0)

// ---------------- LayerNorm + cast to bf16 (1 wave / row) ----------------
__global__ __launch_bounds__(256) void ln_kernel(
    const float* __restrict__ x, const float* __restrict__ gam,
    const float* __restrict__ bet, uint16_t* __restrict__ xn) {
  const int row = blockIdx.x * 4 + (threadIdx.x >> 6);
  const int lane = threadIdx.x & 63;
  const float4* xr = (const float4*)(x + (size_t)row * DM);
  float4 a0 = xr[lane * 2 + 0];
  float4 a1 = xr[lane * 2 + 1];
  float s = a0.x + a0.y + a0.z + a0.w + a1.x + a1.y + a1.z + a1.w;
  float q = a0.x * a0.x + a0.y * a0.y + a0.z * a0.z + a0.w * a0.w +
            a1.x * a1.x + a1.y * a1.y + a1.z * a1.z + a1.w * a1.w;
#pragma unroll
  for (int m = 1; m < 64; m <<= 1) {
    s += __shfl_xor(s, m);
    q += __shfl_xor(q, m);
  }
  const float mean = s * (1.0f / DM);
  const float var = q * (1.0f / DM) - mean * mean;
  const float rstd = rsqrtf(var + 1e-5f);
  const float4* gv = (const float4*)gam;
  const float4* bv = (const float4*)bet;
  float4 g0 = gv[lane * 2], g1 = gv[lane * 2 + 1];
  float4 b0 = bv[lane * 2], b1 = bv[lane * 2 + 1];
  u16x8 r;
  r[0] = f2bf((a0.x - mean) * rstd * g0.x + b0.x);
  r[1] = f2bf((a0.y - mean) * rstd * g0.y + b0.y);
  r[2] = f2bf((a0.z - mean) * rstd * g0.z + b0.z);
  r[3] = f2bf((a0.w - mean) * rstd * g0.w + b0.w);
  r[4] = f2bf((a1.x - mean) * rstd * g1.x + b1.x);
  r[5] = f2bf((a1.y - mean) * rstd * g1.y + b1.y);
  r[6] = f2bf((a1.z - mean) * rstd * g1.z + b1.z);
  r[7] = f2bf((a1.w - mean) * rstd * g1.w + b1.w);
  *(u16x8*)(xn + (size_t)row * DM + lane * 8) = r;
}

// ---------------- weight fp32 -> bf16 cast ----------------
__global__ __launch_bounds__(256) void cast_w(const float* __restrict__ w,
                                              uint16_t* __restrict__ o, int n8) {
  int i = blockIdx.x * 256 + threadIdx.x;
  if (i >= n8) return;
  const float4* p = (const float4*)w + (size_t)i * 2;
  float4 a0 = p[0], a1 = p[1];
  u16x8 r;
  r[0] = f2bf(a0.x); r[1] = f2bf(a0.y); r[2] = f2bf(a0.z); r[3] = f2bf(a0.w);
  r[4] = f2bf(a1.x); r[5] = f2bf(a1.y); r[6] = f2bf(a1.z); r[7] = f2bf(a1.w);
  *(u16x8*)(o + (size_t)i * 8) = r;
}

// ---------------- bf16 NT GEMM: C[M,N] = A[M,512] * Bw[N,512]^T + bias ----------------
// 128x128 tile, BK=64, 4 waves (2x2 of 64x64), global_load_lds w/ pre-swizzled src.
// EPI==0: scatter to Q[BH][S][64] (pre-scaled by QSCALE), K[BH][S][64], V^T[BH][64][S]
// EPI==1: C fp32 row-major [M][512]
template <int EPI>
__global__ __launch_bounds__(256) void gemm_nt(
    const uint16_t* __restrict__ A, const uint16_t* __restrict__ Bw,
    const float* __restrict__ bias, uint16_t* __restrict__ oq,
    uint16_t* __restrict__ okk, uint16_t* __restrict__ ov,
    float* __restrict__ oc) {
  __shared__ __align__(16) char As[128 * 64 * 2];
  __shared__ __align__(16) char Bs[128 * 64 * 2];
  const int tid = threadIdx.x;
  const int lane = tid & 63;
  const int w = tid >> 6;
  const int wr = (w >> 1) * 64;
  const int wc = (w & 1) * 64;
  const int l15 = lane & 15;
  const int l4 = lane >> 4;
  const size_t tileM = (size_t)blockIdx.y * 128;
  const int tileN = blockIdx.x * 128;
  const int trow = tid >> 3;
  const int tcol = tid & 7;
  const f32x4 vzero = {0.f, 0.f, 0.f, 0.f};

  f32x4 acc[4][4];
#pragma unroll
  for (int m = 0; m < 4; ++m)
#pragma unroll
    for (int n = 0; n < 4; ++n) acc[m][n] = vzero;

  for (int kt = 0; kt < 8; ++kt) {
    if (kt) __syncthreads();
#pragma unroll
    for (int i = 0; i < 4; ++i) {
      const int row = i * 32 + trow;
      const int c0 = 8 * (tcol ^ (row & 7));  // pre-swizzled source column
      load_lds16(A + (tileM + row) * DM + kt * 64 + c0, As + i * 4096 + w * 1024);
      load_lds16(Bw + (size_t)(tileN + row) * DM + kt * 64 + c0, Bs + i * 4096 + w * 1024);
    }
    VM_DRAIN();
    __syncthreads();
#pragma unroll
    for (int ks = 0; ks < 2; ++ks) {
      const int kb = ks * 64 + l4 * 16;
      bf16x8 af[4], bfr[4];
#pragma unroll
      for (int m = 0; m < 4; ++m) {
        const int r = wr + m * 16 + l15;
        af[m] = *(const bf16x8*)(As + swz128(r, kb));
      }
#pragma unroll
      for (int n = 0; n < 4; ++n) {
        const int r = wc + n * 16 + l15;
        bfr[n] = *(const bf16x8*)(Bs + swz128(r, kb));
      }
#pragma unroll
      for (int m = 0; m < 4; ++m)
#pragma unroll
        for (int n = 0; n < 4; ++n)
          acc[m][n] = MFMA16(af[m], bfr[n], acc[m][n]);
    }
  }

#pragma unroll
  for (int m = 0; m < 4; ++m) {
    const size_t row0 = tileM + wr + m * 16 + l4 * 4;
#pragma unroll
    for (int n = 0; n < 4; ++n) {
      const int col = tileN + wc + n * 16 + l15;
      const float bb = bias[col];
#pragma unroll
      for (int jj = 0; jj < 4; ++jj) {
        const float val = acc[m][n][jj] + bb;
        const size_t r = row0 + jj;
        if (EPI == 0) {
          const int wh = col >> 9;
          const int rem = col & 511;
          const int h = rem >> 6;
          const int dd = rem & 63;
          const int bi = (int)(r >> 11);
          const int si = (int)(r & 2047);
          const size_t bh = (size_t)bi * NH + h;
          if (wh == 0)
            oq[(bh * SEQ + si) * HD + dd] = f2bf(val * QSCALE);  // exp2-domain Q
          else if (wh == 1)
            okk[(bh * SEQ + si) * HD + dd] = f2bf(val);
          else
            ov[(bh * HD + dd) * SEQ + si] = f2bf(val);  // V stored transposed
        } else {
          oc[r * DM + col] = val;
        }
      }
    }
  }
}

// ---------------- flash attention: 1 block = 128 Q rows of one (b,h) ----------------
// FINAL (= round-16, best verified: 211.5us total, attn 141us, absmax 4.88e-4,
// replay-stable). Swapped-QK^T 32x32 MFMA; lane-local softmax (shfl cross-half);
// P->PV A-fragments in registers (cvt_pk + distinct-value permlane32_swap);
// lane-local fp32 denominator; K/V double-buffer with one barrier per tile;
// __launch_bounds__(256,4) -> VGPR 64, ~32% occupancy, no spills.
// Measured dead ends (do not revisit): skip-rescale (r7/r11/r17 all regressed:
// branch breaks tile-loop scheduling), direct-from-L2 K/V frags (r15: latency-
// exposed, 2x slower), permlane cross-half combine (r8/r18: upper half-wave
// reads its own value unless BOTH swap outputs are consumed).
__global__ __launch_bounds__(256, 4) void attn_kernel(
    const uint16_t* __restrict__ qb, const uint16_t* __restrict__ kb,
    const uint16_t* __restrict__ vb, uint16_t* __restrict__ ab) {
  __shared__ __align__(16) char Ks[2 * 64 * 128];  // [buf][k 64][d 64] bf16, swizzled
  __shared__ __align__(16) char Vs[2 * 64 * 128];  // [buf][d 64][k 64] bf16 (V^T), swizzled
  __shared__ float corrbuf[4 * 32];                // per-wave transpose slot
  const int tid = threadIdx.x;
  const int lane = tid & 63;
  const int wq = tid >> 6;       // wave 0..3 owns q rows wq*32..wq*32+31
  const int l31 = lane & 31;
  const int h = lane >> 5;       // half-wave
  const int bh = blockIdx.x >> 4;
  const int qt = blockIdx.x & 15;
  const uint16_t* qp = qb + (size_t)bh * SEQ * HD;
  const uint16_t* kp = kb + (size_t)bh * SEQ * HD;
  const uint16_t* vp = vb + (size_t)bh * HD * SEQ;
  const int trow = tid >> 3;
  const int tcol = tid & 7;

  auto stageK = [&](int tt, char* dst) {
    const int kv0 = tt * 64;
#pragma unroll
    for (int i = 0; i < 2; ++i) {
      const int row = i * 32 + trow;
      const int c0 = 8 * (tcol ^ (row & 7));
      load_lds16(kp + (size_t)(kv0 + row) * HD + c0, dst + i * 4096 + wq * 1024);
    }
  };
  auto stageV = [&](int tt, char* dst) {
    const int kv0 = tt * 64;
#pragma unroll
    for (int i = 0; i < 2; ++i) {
      const int row = i * 32 + trow;
      const int c0 = 8 * (tcol ^ (row & 7));
      load_lds16(vp + (size_t)row * SEQ + kv0 + c0, dst + i * 4096 + wq * 1024);
    }
  };

  // Q fragments (B-operand: B[col=q=lane&31][k=(lane>>5)*8+j]), whole kernel in regs
  bf16x8 qf[4];
  const int q0 = qt * 128 + wq * 32;
#pragma unroll
  for (int c = 0; c < 4; ++c)
    qf[c] = *(const bf16x8*)(qp + (size_t)(q0 + l31) * HD + c * 16 + h * 8);

  f32x16 oacc0, oacc1;
#pragma unroll
  for (int r = 0; r < 16; ++r) { oacc0[r] = 0.f; oacc1[r] = 0.f; }
  float mrow = -1e30f;  // running max for q = q0 + l31 (dup across halves)
  float lsum = 0.f;     // running denominator for q = q0 + l31 (dup across halves)

  // pack 16 P-values into two PV A-fragments; accumulate their fp32 sum into rs
  auto build2 = [&](const f32x16& s, float m, bf16x8* fa, bf16x8* fb, float& rs) {
    uint32_t u[8];
#pragma unroll
    for (int i2 = 0; i2 < 8; ++i2) {
      float plo = exp2f(s[2 * i2] - m);
      float phi = exp2f(s[2 * i2 + 1] - m);
      rs += plo + phi;
      asm("v_cvt_pk_bf16_f32 %0, %1, %2" : "=v"(u[i2]) : "v"(plo), "v"(phi));
    }
    // swap vdst.hi(lanes32-63) <-> vsrc.lo(lanes0-31): builds contiguous-k frag words
    asm("v_permlane32_swap_b32 %0, %1" : "+v"(u[0]), "+v"(u[2]));
    asm("v_permlane32_swap_b32 %0, %1" : "+v"(u[1]), "+v"(u[3]));
    asm("v_permlane32_swap_b32 %0, %1" : "+v"(u[4]), "+v"(u[6]));
    asm("v_permlane32_swap_b32 %0, %1" : "+v"(u[5]), "+v"(u[7]));
    union { uint32_t w[4]; bf16x8 v; } A, B;
    A.w[0] = u[0]; A.w[1] = u[1]; A.w[2] = u[2]; A.w[3] = u[3];
    B.w[0] = u[4]; B.w[1] = u[5]; B.w[2] = u[6]; B.w[3] = u[7];
    *fa = A.v; *fb = B.v;
  };

  // one KV tile: QK^T -> softmax -> PV, reading Kc/Vc
  auto tile = [&](const char* Kc, const char* Vc) {
    f32x16 s0, s1;
#pragma unroll
    for (int r = 0; r < 16; ++r) { s0[r] = 0.f; s1[r] = 0.f; }
#pragma unroll
    for (int c = 0; c < 4; ++c) {
      const int kbyte = c * 32 + h * 16;
      bf16x8 kf0 = *(const bf16x8*)(Kc + swz128(l31, kbyte));
      bf16x8 kf1 = *(const bf16x8*)(Kc + swz128(32 + l31, kbyte));
      s0 = MFMA32(kf0, qf[c], s0);
      s1 = MFMA32(kf1, qf[c], s1);
    }

    float r8[8];
#pragma unroll
    for (int i = 0; i < 8; ++i)
      r8[i] = fmaxf(fmaxf(s0[2 * i], s0[2 * i + 1]), fmaxf(s1[2 * i], s1[2 * i + 1]));
    float mx = fmaxf(fmaxf(fmaxf(r8[0], r8[1]), fmaxf(r8[2], r8[3])),
                     fmaxf(fmaxf(r8[4], r8[5]), fmaxf(r8[6], r8[7])));
    mx = fmaxf(mx, __shfl_xor(mx, 32));
    const float mold = mrow;
    const float mnew = fmaxf(mold, mx);
    const float corr = exp2f(mold - mnew);
    mrow = mnew;

    // transpose corr (lane-indexed by q) into D-layout via per-wave LDS slot
    corrbuf[wq * 32 + l31] = corr;  // both halves write identical values
    float4 cg[4];
#pragma unroll
    for (int g = 0; g < 4; ++g)
      cg[g] = *(const float4*)(corrbuf + wq * 32 + 8 * g + 4 * h);
#pragma unroll
    for (int rg = 0; rg < 4; ++rg)
#pragma unroll
      for (int rj = 0; rj < 4; ++rj) {
        const float cc = cg[rg][rj];
        const int r = rg * 4 + rj;
        oacc0[r] *= cc; oacc1[r] *= cc;
      }

    // P = exp2(S - m) packed to bf16 PV A-fragments; fp32 row-sum on the side
    float rs = 0.f;
    bf16x8 pa[4];
    build2(s0, mrow, &pa[0], &pa[1], rs);
    build2(s1, mrow, &pa[2], &pa[3], rs);
    rs += __shfl_xor(rs, 32);   // combine k-halves (identical across h after this)
    lsum = lsum * corr + rs;

#pragma unroll
    for (int i = 0; i < 4; ++i) {
      const int kbyte = i * 32 + h * 16;
      bf16x8 v0 = *(const bf16x8*)(Vc + swz128(l31, kbyte));
      bf16x8 v1 = *(const bf16x8*)(Vc + swz128(32 + l31, kbyte));
      oacc0 = MFMA32(pa[i], v0, oacc0);
      oacc1 = MFMA32(pa[i], v1, oacc1);
    }
  };

  char* K0 = Ks;        char* V0 = Vs;
  char* K1 = Ks + 8192; char* V1 = Vs + 8192;

  stageK(0, K0);
  stageV(0, V0);
  VM_DRAIN();
  __syncthreads();

  for (int t = 0; t < SEQ / 64; t += 2) {
    // body A: compute tile t from buf0; prefetch t+1 into buf1 (full tile in flight)
    stageK(t + 1, K1);
    stageV(t + 1, V1);
    tile(K0, V0);
    VM_DRAIN();       // t+1 landed; all waves done reading buf0
    __syncthreads();

    // body B: compute tile t+1 from buf1; prefetch t+2 into buf0
    if (t + 2 < SEQ / 64) {
      stageK(t + 2, K0);
      stageV(t + 2, V0);
    }
    tile(K1, V1);
    VM_DRAIN();
    __syncthreads();
  }

  // transpose lsum (lane-indexed by q) into D-layout via per-wave LDS slot
  corrbuf[wq * 32 + l31] = lsum;  // both halves write identical values
  __builtin_amdgcn_s_waitcnt(0);  // lgkmcnt(0): wave-local write->read ordering

  // epilogue: normalize and write attn output as [T][512] bf16 (col = head*64+d)
  const int bi = bh >> 3;
  const int head = bh & 7;
#pragma unroll
  for (int r = 0; r < 16; ++r) {
    const int q = (r & 3) + 8 * (r >> 2) + 4 * h;
    const float inv = 1.0f / corrbuf[wq * 32 + q];
    const size_t tok = (size_t)bi * SEQ + qt * 128 + wq * 32 + q;
    ab[tok * DM + head * HD + l31] = f2bf(oacc0[r] * inv);
    ab[tok * DM + head * HD + 32 + l31] = f2bf(oacc1[r] * inv);
  }
}

extern "C" void kernel_launch(void* const* d_in, const int* in_sizes, int n_in,
                              void* d_out, int out_size, void* d_ws, size_t ws_size,
                              hipStream_t stream) {
  const float* x = (const float*)d_in[0];
  const float* gam = (const float*)d_in[1];
  const float* bet = (const float*)d_in[2];
  const float* wqkv = (const float*)d_in[3];
  const float* bqkv = (const float*)d_in[4];
  const float* wout = (const float*)d_in[5];
  const float* bout = (const float*)d_in[6];

  const size_t SZ_XN = (size_t)TOK * DM * 2;               // 16 MiB
  const size_t SZ_WQ = (size_t)3 * DM * DM * 2;            // 1.5 MiB
  const size_t SZ_WO = (size_t)DM * DM * 2;                // 0.5 MiB
  const size_t SZ_HDBUF = (size_t)BATCH * NH * SEQ * HD * 2;  // 16 MiB each

  char* p = (char*)d_ws;
  uint16_t* xn = (uint16_t*)p;      p += SZ_XN;
  uint16_t* wq = (uint16_t*)p;      p += SZ_WQ;
  uint16_t* wo = (uint16_t*)p;      p += SZ_WO;
  uint16_t* qbuf = (uint16_t*)p;    p += SZ_HDBUF;
  uint16_t* kbuf = (uint16_t*)p;    p += SZ_HDBUF;
  uint16_t* vbuf = (uint16_t*)p;    p += SZ_HDBUF;
  uint16_t* abuf = xn;  // xn dead after QKV GEMM; reuse for attention output

  ln_kernel<<<dim3(TOK / 4), dim3(256), 0, stream>>>(x, gam, bet, xn);
  cast_w<<<dim3((3 * DM * DM / 8) / 256), dim3(256), 0, stream>>>(wqkv, wq, 3 * DM * DM / 8);
  cast_w<<<dim3((DM * DM / 8) / 256), dim3(256), 0, stream>>>(wout, wo, DM * DM / 8);
  gemm_nt<0><<<dim3(12, 128), dim3(256), 0, stream>>>(xn, wq, bqkv, qbuf, kbuf, vbuf, nullptr);
  attn_kernel<<<dim3(BATCH * NH * (SEQ / 128)), dim3(256), 0, stream>>>(qbuf, kbuf, vbuf, abuf);
  gemm_nt<1><<<dim3(4, 128), dim3(256), 0, stream>>>(abuf, wo, bout, nullptr, nullptr, nullptr,
                                                     (float*)d_out);
}